// Round 14
// baseline (260.375 us; speedup 1.0000x reference)
//
#include <hip/hip_runtime.h>

#define DIM 512
#define HH  1024
#define NB  64
#define NV  64

typedef float v2f __attribute__((ext_vector_type(2)));
typedef float v4f __attribute__((ext_vector_type(4)));

// Packed fp32 (VOP3P) — one issue slot, two fp32 elements.
static __device__ __forceinline__ v2f pk_add(v2f a, v2f b) {
    v2f d; asm("v_pk_add_f32 %0, %1, %2" : "=v"(d) : "v"(a), "v"(b)); return d;
}
static __device__ __forceinline__ v2f pk_mul(v2f a, v2f b) {
    v2f d; asm("v_pk_mul_f32 %0, %1, %2" : "=v"(d) : "v"(a), "v"(b)); return d;
}
static __device__ __forceinline__ v2f pk_fma(v2f a, v2f b, v2f c) {
    v2f d; asm("v_pk_fma_f32 %0, %1, %2, %3" : "=v"(d) : "v"(a), "v"(b), "v"(c)); return d;
}

// ws layout (floats):
//   ctx   [64][1024]     @ 0        ((state+action)@Wx + b1)
//   cause [64][1024]     @ 65536    (embed@Wc)
//   effQ4 [256][64][4]   @ 131072   (embed@We as quads: effQ4[h/4][j][h%4])

// K-split prep: grid = 3 m x 16 rowgroups x 8 k-chunks = 384 blocks.
extern "C" __global__ __launch_bounds__(256)
void cgl_prep(const float* __restrict__ state, const float* __restrict__ action,
              const float* __restrict__ embed, const float* __restrict__ W1,
              const float* __restrict__ b1, float* __restrict__ ws)
{
    __shared__ float arow[4][64];
    const int m   = blockIdx.x >> 7;       // 0=cause, 1=effect, 2=ctx
    const int rg  = (blockIdx.x >> 3) & 15;
    const int kc  = blockIdx.x & 7;
    const int tid = threadIdx.x;

    {   // stage 4 rows x 64 k's (exactly 256 values)
        int r = tid >> 6, kk = tid & 63;
        int row = rg * 4 + r, k = kc * 64 + kk;
        arow[r][kk] = (m == 2) ? (state[row * DIM + k] + action[row * DIM + k])
                               : embed[row * DIM + k];
    }
    __syncthreads();

    const float* Wm = W1 + m * DIM * HH + kc * 64 * HH;
    const int c = tid * 4;                 // 4 consecutive h per thread
    float4 acc0 = {0,0,0,0}, acc1 = {0,0,0,0}, acc2 = {0,0,0,0}, acc3 = {0,0,0,0};
    #pragma unroll 4
    for (int kk = 0; kk < 64; ++kk) {
        const float4 w = *reinterpret_cast<const float4*>(Wm + kk * HH + c);
        float a0 = arow[0][kk], a1 = arow[1][kk], a2 = arow[2][kk], a3 = arow[3][kk];
        acc0.x = fmaf(a0, w.x, acc0.x); acc0.y = fmaf(a0, w.y, acc0.y);
        acc0.z = fmaf(a0, w.z, acc0.z); acc0.w = fmaf(a0, w.w, acc0.w);
        acc1.x = fmaf(a1, w.x, acc1.x); acc1.y = fmaf(a1, w.y, acc1.y);
        acc1.z = fmaf(a1, w.z, acc1.z); acc1.w = fmaf(a1, w.w, acc1.w);
        acc2.x = fmaf(a2, w.x, acc2.x); acc2.y = fmaf(a2, w.y, acc2.y);
        acc2.z = fmaf(a2, w.z, acc2.z); acc2.w = fmaf(a2, w.w, acc2.w);
        acc3.x = fmaf(a3, w.x, acc3.x); acc3.y = fmaf(a3, w.y, acc3.y);
        acc3.z = fmaf(a3, w.z, acc3.z); acc3.w = fmaf(a3, w.w, acc3.w);
    }

    float* ctx   = ws;
    float* cause = ws + NB * HH;
    float* effQ  = ws + 2 * NB * HH;
    float4 accs[4] = {acc0, acc1, acc2, acc3};

    if (m == 2 && kc == 0) {   // add bias exactly once
        const float4 bv = *reinterpret_cast<const float4*>(b1 + c);
        #pragma unroll
        for (int r = 0; r < 4; ++r) {
            accs[r].x += bv.x; accs[r].y += bv.y;
            accs[r].z += bv.z; accs[r].w += bv.w;
        }
    }

    #pragma unroll
    for (int r = 0; r < 4; ++r) {
        const int row = rg * 4 + r;
        if (m == 1) {
            // effQ4[h4 = tid][row][0..3] — the quad is exactly accs[r]
            float* base = effQ + (tid * 64 + row) * 4;
            atomicAdd(base + 0, accs[r].x);
            atomicAdd(base + 1, accs[r].y);
            atomicAdd(base + 2, accs[r].z);
            atomicAdd(base + 3, accs[r].w);
        } else {
            float* base = ((m == 0) ? cause : ctx) + row * HH + c;
            atomicAdd(base + 0, accs[r].x);
            atomicAdd(base + 1, accs[r].y);
            atomicAdd(base + 2, accs[r].z);
            atomicAdd(base + 3, accs[r].w);
        }
    }
}

// TRANS-FREE gelu sigma: sigma(w) for w = x*(1.5958+0.0714x^2),
//   sa = 1/(1+e^{-|w|}),  e^{-|w|} = (poly6(|w|/16))^16,
//   1/d on (1,2] via cubic seed + 1 Newton,  sigma = 0.5 + copysign(sa-0.5, x).
// All full-rate VALU (pk-packed); zero trans-pipe ops in the hot loop.
extern "C" __global__ __launch_bounds__(512, 8)
void cgl_score(const float* __restrict__ ws, const float* __restrict__ W2,
               const float* __restrict__ b2, float* __restrict__ out)
{
    __shared__ v4f pre4[4][256];    // 16 KB: ctx[b]+cause[i] as quads
    __shared__ v4f eff4[2][8][64];  // 16 KB: eff chunk, both halves
    __shared__ v4f w24[256];        //  4 KB
    __shared__ float red[8][64];    //  2 KB

    const v4f* ctx4g   = (const v4f*)ws;
    const v4f* cause4g = (const v4f*)(ws + NB * HH);
    const v4f* effQ4g  = (const v4f*)(ws + 2 * NB * HH);
    const v4f* W24g    = (const v4f*)W2;

    const int i    = blockIdx.x & 63;
    const int bg   = blockIdx.x >> 6;      // 0..15
    const int tid  = threadIdx.x;
    const int lane = tid & 63;
    const int wave = tid >> 6;
    const int bq   = wave & 3;             // local b
    const int hh   = wave >> 2;            // h half (0/1)

    for (int idx = tid; idx < 1024; idx += 512) {       // 4 b x 256 quads
        int w = idx >> 8, h4 = idx & 255;
        v4f c4 = ctx4g[(bg * 4 + w) * 256 + h4];
        v4f a4 = cause4g[i * 256 + h4];
        pre4[w][h4] = c4 + a4;
    }
    for (int h4 = tid; h4 < 256; h4 += 512) w24[h4] = W24g[h4];

    // constant pairs (hoisted to VGPRs once)
    const v2f KC1 = {0.0713548162f / 16.0f, 0.0713548162f / 16.0f};
    const v2f KC0 = {1.5957691216f / 16.0f, 1.5957691216f / 16.0f};
    const v2f E6  = {1.0f/720.0f, 1.0f/720.0f};
    const v2f E5  = {-1.0f/120.0f, -1.0f/120.0f};
    const v2f E4  = {1.0f/24.0f, 1.0f/24.0f};
    const v2f E3  = {-1.0f/6.0f, -1.0f/6.0f};
    const v2f E2  = {0.5f, 0.5f};
    const v2f EN1 = {-1.0f, -1.0f};
    const v2f ONE = {1.0f, 1.0f};
    const v2f TWO = {2.0f, 2.0f};
    const v2f S3  = {16.0f/81.0f, 16.0f/81.0f};
    const v2f S2  = {32.0f/27.0f, 32.0f/27.0f};
    const v2f S1  = {8.0f/3.0f, 8.0f/3.0f};
    const v2f MH  = {-0.5f, -0.5f};
    const v2f PH  = {0.5f, 0.5f};

    v2f acc01 = {0.0f, 0.0f}, acc23 = {0.0f, 0.0f};

    for (int c = 0; c < 16; ++c) {
        __syncthreads();   // covers initial fills on c==0
        for (int t = tid; t < 1024; t += 512) {          // pure copy, 16 KB
            int q = t >> 9, rem = t & 511, dq = rem >> 6, j = rem & 63;
            eff4[q][dq][j] = effQ4g[(q * 128 + c * 8 + dq) * 64 + j];
        }
        __syncthreads();
        const int hq = hh * 128 + c * 8;
        #pragma unroll
        for (int dq = 0; dq < 8; ++dq) {
            v4f e4 = eff4[hh][dq][lane];                 // ds_read_b128
            v4f p4 = pre4[bq][hq + dq];                  // broadcast b128
            v4f w4 = w24[hq + dq];                       // broadcast b128
            #pragma unroll
            for (int half = 0; half < 2; ++half) {
                v2f ev = half ? v2f{e4.z, e4.w} : v2f{e4.x, e4.y};
                v2f pv = half ? v2f{p4.z, p4.w} : v2f{p4.x, p4.y};
                v2f wv = half ? v2f{w4.z, w4.w} : v2f{w4.x, w4.y};
                v2f x  = pk_add(pv, ev);
                // clamp to [-4,4] (min+max -> v_med3 fusion)
                v2f xc; xc.x = fminf(fmaxf(x.x, -4.0f), 4.0f);
                        xc.y = fminf(fmaxf(x.y, -4.0f), 4.0f);
                v2f s   = pk_mul(xc, xc);
                v2f t1  = pk_fma(s, KC1, KC0);
                v2f w16 = pk_mul(xc, t1);                // w/16 in [-.685,.685]
                v2f z; z.x = fabsf(w16.x); z.y = fabsf(w16.y);
                // e^{-z*16} = (poly6(z))^16
                v2f q6 = pk_fma(E6, z, E5);
                q6 = pk_fma(q6, z, E4);
                q6 = pk_fma(q6, z, E3);
                q6 = pk_fma(q6, z, E2);
                q6 = pk_fma(q6, z, EN1);
                q6 = pk_fma(q6, z, ONE);                 // e^{-z}
                v2f e2 = pk_mul(q6, q6);
                v2f e4v = pk_mul(e2, e2);
                v2f e8 = pk_mul(e4v, e4v);
                v2f e16 = pk_mul(e8, e8);                // e^{-|w|} in (0,1]
                // 1/(1+e16): nd = -(1+e16); cubic seed + 1 Newton
                v2f nd = pk_fma(e16, EN1, EN1);
                v2f r0 = pk_fma(pk_fma(pk_fma(S3, nd, S2), nd, S1), nd, S1);
                v2f h1 = pk_fma(nd, r0, TWO);
                v2f sa = pk_mul(r0, h1);                 // sigma(|w|) in [.5,1)
                // sigma = 0.5 + copysign(sa-0.5, x)
                v2f sm = pk_add(sa, MH);
                v2f sc; sc.x = __builtin_copysignf(sm.x, x.x);
                        sc.y = __builtin_copysignf(sm.y, x.y);
                v2f sg = pk_add(sc, PH);
                v2f g  = pk_mul(x, sg);                  // gelu(x)
                if (half) acc23 = pk_fma(g, wv, acc23);
                else      acc01 = pk_fma(g, wv, acc01);
            }
        }
    }

    red[wave][lane] = (acc01.x + acc01.y) + (acc23.x + acc23.y);
    __syncthreads();
    if (wave < 4) {
        float logit = red[wave][lane] + red[wave + 4][lane] + b2[0];
        float sgm = __builtin_amdgcn_rcpf(
            1.0f + __builtin_amdgcn_exp2f(-1.4426950408889634f * logit));
        atomicAdd(&out[i * 64 + lane], sgm * (1.0f / 64.0f));
    }
}

extern "C" void kernel_launch(void* const* d_in, const int* in_sizes, int n_in,
                              void* d_out, int out_size, void* d_ws, size_t ws_size,
                              hipStream_t stream) {
    const float* state  = (const float*)d_in[0];
    const float* action = (const float*)d_in[1];
    const float* embed  = (const float*)d_in[2];
    const float* W1     = (const float*)d_in[3];
    const float* b1     = (const float*)d_in[4];
    const float* W2     = (const float*)d_in[5];
    const float* b2     = (const float*)d_in[6];
    float* ws = (float*)d_ws;

    hipMemsetAsync(d_out, 0, out_size * sizeof(float), stream);
    hipMemsetAsync(d_ws, 0, 3 * NB * HH * sizeof(float), stream);
    cgl_prep<<<384, 256, 0, stream>>>(state, action, embed, W1, b1, ws);
    cgl_score<<<64 * 16, 512, 0, stream>>>(ws, W2, b2, (float*)d_out);
}